// Round 1
// baseline (310.930 us; speedup 1.0000x reference)
//
#include <hip/hip_runtime.h>

typedef unsigned short u16;
typedef unsigned int u32;

typedef __bf16 bf16x8 __attribute__((ext_vector_type(8)));
typedef float f32x4 __attribute__((ext_vector_type(4)));

__device__ __forceinline__ u16 f2bf(float f) {
  u32 u = __builtin_bit_cast(u32, f);
  u32 r = (u + 0x7fffu + ((u >> 16) & 1u)) >> 16;  // RNE
  return (u16)r;
}

// ---------------- f32 -> bf16 convert (n % 4 == 0, grid exact) ----------------
__global__ __launch_bounds__(256) void cvt_kernel(const float* __restrict__ src,
                                                  u16* __restrict__ dst, int n) {
  int i = (blockIdx.x * 256 + threadIdx.x) * 4;
  if (i + 3 < n) {
    float4 v = *(const float4*)(src + i);
    dst[i + 0] = f2bf(v.x);
    dst[i + 1] = f2bf(v.y);
    dst[i + 2] = f2bf(v.z);
    dst[i + 3] = f2bf(v.w);
  }
}

// ---------------- bf16 MFMA GEMM: C[M][N] = A[M][K] * B[N][K]^T ----------------
// 128x128 block tile, BK=32, 4 waves in 2x2, each wave 64x64 via 4x4 mfma_16x16x32.
__global__ __launch_bounds__(256)
void gemm_bt_kernel(const u16* __restrict__ A, const u16* __restrict__ B,
                    float* __restrict__ C, int M, int N, int K) {
  __shared__ u16 As[128 * 32];
  __shared__ u16 Bs[128 * 32];
  const int tid = threadIdx.x;
  const int lane = tid & 63;
  const int wave = tid >> 6;
  const int wm = (wave >> 1) * 64;
  const int wn = (wave & 1) * 64;
  const int l15 = lane & 15;
  const int qk = (lane >> 4) * 8;
  const size_t bm = (size_t)blockIdx.y * 128;
  const size_t bn = (size_t)blockIdx.x * 128;

  f32x4 acc[4][4];
#pragma unroll
  for (int i = 0; i < 4; ++i)
#pragma unroll
    for (int j = 0; j < 4; ++j) acc[i][j] = f32x4{0.f, 0.f, 0.f, 0.f};

  const int r0 = tid >> 2;        // 0..63
  const int c0 = (tid & 3) * 8;   // 0,8,16,24
  const u16* Ab = A + (bm + r0) * (size_t)K + c0;
  const u16* Bb = B + (bn + r0) * (size_t)K + c0;

  for (int k0 = 0; k0 < K; k0 += 32) {
    __syncthreads();
    *(uint4*)(&As[tid * 8]) = *(const uint4*)(Ab + k0);
    *(uint4*)(&As[tid * 8 + 2048]) = *(const uint4*)(Ab + (size_t)64 * K + k0);
    *(uint4*)(&Bs[tid * 8]) = *(const uint4*)(Bb + k0);
    *(uint4*)(&Bs[tid * 8 + 2048]) = *(const uint4*)(Bb + (size_t)64 * K + k0);
    __syncthreads();
    bf16x8 af[4], bfr[4];
#pragma unroll
    for (int i = 0; i < 4; ++i)
      af[i] = *(const bf16x8*)(&As[(wm + i * 16 + l15) * 32 + qk]);
#pragma unroll
    for (int j = 0; j < 4; ++j)
      bfr[j] = *(const bf16x8*)(&Bs[(wn + j * 16 + l15) * 32 + qk]);
#pragma unroll
    for (int i = 0; i < 4; ++i)
#pragma unroll
      for (int j = 0; j < 4; ++j)
        acc[i][j] = __builtin_amdgcn_mfma_f32_16x16x32_bf16(af[i], bfr[j], acc[i][j], 0, 0, 0);
  }

  const int rq = (lane >> 4) * 4;  // row = quad*4 + reg
#pragma unroll
  for (int i = 0; i < 4; ++i) {
#pragma unroll
    for (int r = 0; r < 4; ++r) {
      float* crow = C + (bm + wm + i * 16 + rq + r) * (size_t)N + bn + wn + l15;
#pragma unroll
      for (int j = 0; j < 4; ++j) crow[j * 16] = acc[i][j][r];
    }
  }
}

// ---------------- in-place RMSNorm of q (1024) and k (256) per token ----------------
__global__ __launch_bounds__(256)
void rmsnorm_kernel(float* __restrict__ qkv, const float* __restrict__ qw,
                    const float* __restrict__ kw) {
  __shared__ float red[4];
  const int tid = threadIdx.x;
  float* row = qkv + (size_t)blockIdx.x * 1536;
  float4 v = *(const float4*)(row + tid * 4);
  float ss = v.x * v.x + v.y * v.y + v.z * v.z + v.w * v.w;
#pragma unroll
  for (int off = 32; off > 0; off >>= 1) ss += __shfl_down(ss, off);
  if ((tid & 63) == 0) red[tid >> 6] = ss;
  __syncthreads();
  float tot = red[0] + red[1] + red[2] + red[3];
  float rn = rsqrtf(tot * (1.0f / 1024.0f) + 1e-6f);
  float4 w = *(const float4*)(qw + tid * 4);
  v.x *= rn * w.x; v.y *= rn * w.y; v.z *= rn * w.z; v.w *= rn * w.w;
  *(float4*)(row + tid * 4) = v;
  if (tid < 64) {
    float4 kv = *(const float4*)(row + 1024 + tid * 4);
    float sk = kv.x * kv.x + kv.y * kv.y + kv.z * kv.z + kv.w * kv.w;
#pragma unroll
    for (int off = 32; off > 0; off >>= 1) sk += __shfl_down(sk, off);
    float tk = __shfl(sk, 0);
    float rk = rsqrtf(tk * (1.0f / 256.0f) + 1e-6f);
    float4 w2 = *(const float4*)(kw + tid * 4);
    kv.x *= rk * w2.x; kv.y *= rk * w2.y; kv.z *= rk * w2.z; kv.w *= rk * w2.w;
    *(float4*)(row + 1024 + tid * 4) = kv;
  }
}

// ---------------- flash attention (f32, ALiBi, causal + sliding window 512, GQA) ----------------
// grid: (qtile=32, h=16, b=2), block 256. 64-query tile, 64-key chunks.
// LDS: Qs + KPs (K, then reused for P) + Vs = 3 * 64*68*4B = 52.2 KB.
__global__ __launch_bounds__(256)
void attn_kernel(const float* __restrict__ qkv, u16* __restrict__ ybf) {
  __shared__ float Qs[64][68];
  __shared__ float KPs[64][68];
  __shared__ float Vs[64][68];
  const int qt = blockIdx.x, h = blockIdx.y, b = blockIdx.z;
  const int kvh = h >> 2;
  const int q0 = qt * 64;
  const int tid = threadIdx.x;
  const int lr = tid >> 2;
  const int lc = (tid & 3) * 16;
  {
    const float* src = qkv + ((size_t)(b * 2048 + q0 + lr)) * 1536 + h * 64 + lc;
#pragma unroll
    for (int ii = 0; ii < 4; ++ii)
      *(float4*)(&Qs[lr][lc + ii * 4]) = *(const float4*)(src + ii * 4);
  }
  const int g = tid >> 4;     // 16-lane group -> q rows bq..bq+3
  const int bq = g * 4;
  const int sub = tid & 15;   // key cols {sub, sub+16, sub+32, sub+48}; out cols bd..bd+3
  const int bd = sub * 4;
  float m_i[4], l_i[4], O[4][4];
#pragma unroll
  for (int i = 0; i < 4; ++i) {
    m_i[i] = -1e30f;
    l_i[i] = 0.f;
#pragma unroll
    for (int j = 0; j < 4; ++j) O[i][j] = 0.f;
  }
  const float slope = exp2f(-0.5f * (float)(h + 1));
  const int c_lo = (q0 >= 512) ? (q0 - 512) : 0;

  for (int c = c_lo; c <= q0; c += 64) {
    __syncthreads();  // prev PV reads of KPs/Vs done
    {
      const float* kb = qkv + ((size_t)(b * 2048 + c + lr)) * 1536 + 1024 + kvh * 64 + lc;
      const float* vb = kb + 256;
#pragma unroll
      for (int ii = 0; ii < 4; ++ii)
        *(float4*)(&KPs[lr][lc + ii * 4]) = *(const float4*)(kb + ii * 4);
#pragma unroll
      for (int ii = 0; ii < 4; ++ii)
        *(float4*)(&Vs[lr][lc + ii * 4]) = *(const float4*)(vb + ii * 4);
    }
    __syncthreads();
    // scores: s[i][j] = Q[bq+i] . K[sub+16j]
    float s[4][4] = {};
    for (int d = 0; d < 64; d += 4) {
      float qv[4][4], kv[4][4];
#pragma unroll
      for (int i = 0; i < 4; ++i) {
        float4 t = *(const float4*)(&Qs[bq + i][d]);
        qv[i][0] = t.x; qv[i][1] = t.y; qv[i][2] = t.z; qv[i][3] = t.w;
      }
#pragma unroll
      for (int j = 0; j < 4; ++j) {
        float4 t = *(const float4*)(&KPs[sub + 16 * j][d]);
        kv[j][0] = t.x; kv[j][1] = t.y; kv[j][2] = t.z; kv[j][3] = t.w;
      }
#pragma unroll
      for (int i = 0; i < 4; ++i)
#pragma unroll
        for (int j = 0; j < 4; ++j)
#pragma unroll
          for (int dd = 0; dd < 4; ++dd) s[i][j] += qv[i][dd] * kv[j][dd];
    }
    __syncthreads();  // all K reads done; KPs becomes P
    // online softmax per q row (shared across the 16-lane group)
#pragma unroll
    for (int i = 0; i < 4; ++i) {
      const int qq = q0 + bq + i;
      float sv[4], rm = -1e30f;
#pragma unroll
      for (int j = 0; j < 4; ++j) {
        const int kk = c + sub + 16 * j;
        const int rel = kk - qq;
        float val = (rel > 0 || rel < -512) ? -1e30f
                                            : s[i][j] * 0.125f + slope * (float)rel;
        sv[j] = val;
        rm = fmaxf(rm, val);
      }
      rm = fmaxf(rm, __shfl_xor(rm, 1, 16));
      rm = fmaxf(rm, __shfl_xor(rm, 2, 16));
      rm = fmaxf(rm, __shfl_xor(rm, 4, 16));
      rm = fmaxf(rm, __shfl_xor(rm, 8, 16));
      const float mn = fmaxf(m_i[i], rm);
      float ls = 0.f;
#pragma unroll
      for (int j = 0; j < 4; ++j) {
        float p = __expf(sv[j] - mn);
        KPs[bq + i][sub + 16 * j] = p;
        ls += p;
      }
      ls += __shfl_xor(ls, 1, 16);
      ls += __shfl_xor(ls, 2, 16);
      ls += __shfl_xor(ls, 4, 16);
      ls += __shfl_xor(ls, 8, 16);
      const float alpha = __expf(m_i[i] - mn);
      l_i[i] = l_i[i] * alpha + ls;
      m_i[i] = mn;
#pragma unroll
      for (int j = 0; j < 4; ++j) O[i][j] *= alpha;
    }
    __syncthreads();  // P visible to all
    // PV: O[i][j] += sum_k P[bq+i][k] * V[k][bd+j]
    for (int k = 0; k < 64; k += 4) {
      float pr[4][4], vr[4][4];
#pragma unroll
      for (int i = 0; i < 4; ++i) {
        float4 t = *(const float4*)(&KPs[bq + i][k]);
        pr[i][0] = t.x; pr[i][1] = t.y; pr[i][2] = t.z; pr[i][3] = t.w;
      }
#pragma unroll
      for (int kk = 0; kk < 4; ++kk) {
        float4 t = *(const float4*)(&Vs[k + kk][bd]);
        vr[kk][0] = t.x; vr[kk][1] = t.y; vr[kk][2] = t.z; vr[kk][3] = t.w;
      }
#pragma unroll
      for (int i = 0; i < 4; ++i)
#pragma unroll
        for (int j = 0; j < 4; ++j)
#pragma unroll
          for (int kk = 0; kk < 4; ++kk) O[i][j] += pr[i][kk] * vr[kk][j];
    }
  }

#pragma unroll
  for (int i = 0; i < 4; ++i) {
    const float inv = 1.0f / l_i[i];
    u16* orow = ybf + ((size_t)(b * 2048 + q0 + bq + i)) * 1024 + h * 64 + bd;
#pragma unroll
    for (int j = 0; j < 4; ++j) orow[j] = f2bf(O[i][j] * inv);
  }
}

// ---------------- launch ----------------
extern "C" void kernel_launch(void* const* d_in, const int* in_sizes, int n_in,
                              void* d_out, int out_size, void* d_ws, size_t ws_size,
                              hipStream_t stream) {
  const float* x = (const float*)d_in[0];
  const float* wq = (const float*)d_in[1];
  const float* wk = (const float*)d_in[2];
  const float* wv = (const float*)d_in[3];
  const float* wo = (const float*)d_in[4];
  const float* qnw = (const float*)d_in[5];
  const float* knw = (const float*)d_in[6];
  float* out = (float*)d_out;
  char* ws = (char*)d_ws;

  // workspace layout (bytes): total ~45 MB
  u16* x_bf = (u16*)(ws);                    // 4194304 elems
  u16* wcat_bf = (u16*)(ws + 8388608);       // 1536x1024 = 1572864 elems
  u16* wo_bf = (u16*)(ws + 11534336);        // 1048576 elems
  float* qkv = (float*)(ws + 13631488);      // 4096x1536 f32
  u16* y_bf = (u16*)(ws + 38797312);         // 4096x1024 bf16

  cvt_kernel<<<4096, 256, 0, stream>>>(x, x_bf, 4194304);
  cvt_kernel<<<1024, 256, 0, stream>>>(wq, wcat_bf, 1048576);
  cvt_kernel<<<256, 256, 0, stream>>>(wk, wcat_bf + 1048576, 262144);
  cvt_kernel<<<256, 256, 0, stream>>>(wv, wcat_bf + 1310720, 262144);
  cvt_kernel<<<1024, 256, 0, stream>>>(wo, wo_bf, 1048576);

  gemm_bt_kernel<<<dim3(12, 32), 256, 0, stream>>>(x_bf, wcat_bf, qkv, 4096, 1536, 1024);
  rmsnorm_kernel<<<4096, 256, 0, stream>>>(qkv, qnw, knw);
  attn_kernel<<<dim3(32, 16, 2), 256, 0, stream>>>(qkv, y_bf);
  gemm_bt_kernel<<<dim3(8, 32), 256, 0, stream>>>(y_bf, wo_bf, out, 4096, 1024, 1024);
}

// Round 2
// 187.109 us; speedup vs baseline: 1.6618x; 1.6618x over previous
//
#include <hip/hip_runtime.h>

typedef unsigned short u16;
typedef unsigned int u32;

typedef __bf16 bf16x8 __attribute__((ext_vector_type(8)));
typedef float f32x4 __attribute__((ext_vector_type(4)));

__device__ __forceinline__ u16 f2bf(float f) {
  u32 u = __builtin_bit_cast(u32, f);
  u32 r = (u + 0x7fffu + ((u >> 16) & 1u)) >> 16;  // RNE
  return (u16)r;
}
__device__ __forceinline__ float bf2f(u16 v) {
  u32 u = (u32)v << 16;
  return __builtin_bit_cast(float, u);
}

// ---------------- f32 -> bf16 convert ----------------
__global__ __launch_bounds__(256) void cvt_kernel(const float* __restrict__ src,
                                                  u16* __restrict__ dst, int n) {
  int i = (blockIdx.x * 256 + threadIdx.x) * 4;
  if (i + 3 < n) {
    float4 v = *(const float4*)(src + i);
    dst[i + 0] = f2bf(v.x);
    dst[i + 1] = f2bf(v.y);
    dst[i + 2] = f2bf(v.z);
    dst[i + 3] = f2bf(v.w);
  }
}

// ---------------- bf16 MFMA GEMM: C[M][N] = A[M][K] * B[N][K]^T ----------------
template <typename OutT>
__global__ __launch_bounds__(256)
void gemm_bt_kernel(const u16* __restrict__ A, const u16* __restrict__ B,
                    OutT* __restrict__ C, int M, int N, int K) {
  __shared__ u16 As[128 * 32];
  __shared__ u16 Bs[128 * 32];
  const int tid = threadIdx.x;
  const int lane = tid & 63;
  const int wave = tid >> 6;
  const int wm = (wave >> 1) * 64;
  const int wn = (wave & 1) * 64;
  const int l15 = lane & 15;
  const int qk = (lane >> 4) * 8;
  const size_t bm = (size_t)blockIdx.y * 128;
  const size_t bn = (size_t)blockIdx.x * 128;

  f32x4 acc[4][4];
#pragma unroll
  for (int i = 0; i < 4; ++i)
#pragma unroll
    for (int j = 0; j < 4; ++j) acc[i][j] = f32x4{0.f, 0.f, 0.f, 0.f};

  const int r0 = tid >> 2;
  const int c0 = (tid & 3) * 8;
  const u16* Ab = A + (bm + r0) * (size_t)K + c0;
  const u16* Bb = B + (bn + r0) * (size_t)K + c0;

  for (int k0 = 0; k0 < K; k0 += 32) {
    __syncthreads();
    *(uint4*)(&As[tid * 8]) = *(const uint4*)(Ab + k0);
    *(uint4*)(&As[tid * 8 + 2048]) = *(const uint4*)(Ab + (size_t)64 * K + k0);
    *(uint4*)(&Bs[tid * 8]) = *(const uint4*)(Bb + k0);
    *(uint4*)(&Bs[tid * 8 + 2048]) = *(const uint4*)(Bb + (size_t)64 * K + k0);
    __syncthreads();
    bf16x8 af[4], bfr[4];
#pragma unroll
    for (int i = 0; i < 4; ++i)
      af[i] = *(const bf16x8*)(&As[(wm + i * 16 + l15) * 32 + qk]);
#pragma unroll
    for (int j = 0; j < 4; ++j)
      bfr[j] = *(const bf16x8*)(&Bs[(wn + j * 16 + l15) * 32 + qk]);
#pragma unroll
    for (int i = 0; i < 4; ++i)
#pragma unroll
      for (int j = 0; j < 4; ++j)
        acc[i][j] = __builtin_amdgcn_mfma_f32_16x16x32_bf16(af[i], bfr[j], acc[i][j], 0, 0, 0);
  }

  const int rq = (lane >> 4) * 4;
#pragma unroll
  for (int i = 0; i < 4; ++i) {
#pragma unroll
    for (int r = 0; r < 4; ++r) {
      OutT* crow = C + (bm + wm + i * 16 + rq + r) * (size_t)N + bn + wn + l15;
#pragma unroll
      for (int j = 0; j < 4; ++j) {
        if constexpr (sizeof(OutT) == 2)
          crow[j * 16] = f2bf(acc[i][j][r]);
        else
          crow[j * 16] = acc[i][j][r];
      }
    }
  }
}

// ---------------- in-place bf16 RMSNorm of q (1024) and k (256) per token ----------------
__global__ __launch_bounds__(256)
void rmsnorm_kernel(u16* __restrict__ qkv, const float* __restrict__ qw,
                    const float* __restrict__ kw) {
  __shared__ float red[4];
  const int tid = threadIdx.x;
  u16* row = qkv + (size_t)blockIdx.x * 1536;
  uint2 pk = *(const uint2*)(row + tid * 4);
  float v0 = bf2f((u16)pk.x), v1 = bf2f((u16)(pk.x >> 16));
  float v2 = bf2f((u16)pk.y), v3 = bf2f((u16)(pk.y >> 16));
  float ss = v0 * v0 + v1 * v1 + v2 * v2 + v3 * v3;
#pragma unroll
  for (int off = 32; off > 0; off >>= 1) ss += __shfl_down(ss, off);
  if ((tid & 63) == 0) red[tid >> 6] = ss;
  __syncthreads();
  float tot = red[0] + red[1] + red[2] + red[3];
  float rn = rsqrtf(tot * (1.0f / 1024.0f) + 1e-6f);
  float4 w = *(const float4*)(qw + tid * 4);
  uint2 po;
  po.x = (u32)f2bf(v0 * rn * w.x) | ((u32)f2bf(v1 * rn * w.y) << 16);
  po.y = (u32)f2bf(v2 * rn * w.z) | ((u32)f2bf(v3 * rn * w.w) << 16);
  *(uint2*)(row + tid * 4) = po;
  if (tid < 64) {
    uint2 kp = *(const uint2*)(row + 1024 + tid * 4);
    float k0 = bf2f((u16)kp.x), k1 = bf2f((u16)(kp.x >> 16));
    float k2 = bf2f((u16)kp.y), k3 = bf2f((u16)(kp.y >> 16));
    float sk = k0 * k0 + k1 * k1 + k2 * k2 + k3 * k3;
#pragma unroll
    for (int off = 32; off > 0; off >>= 1) sk += __shfl_down(sk, off);
    float tk = __shfl(sk, 0);
    float rk = rsqrtf(tk * (1.0f / 256.0f) + 1e-6f);
    float4 w2 = *(const float4*)(kw + tid * 4);
    uint2 ko;
    ko.x = (u32)f2bf(k0 * rk * w2.x) | ((u32)f2bf(k1 * rk * w2.y) << 16);
    ko.y = (u32)f2bf(k2 * rk * w2.z) | ((u32)f2bf(k3 * rk * w2.w) << 16);
    *(uint2*)(row + 1024 + tid * 4) = ko;
  }
}

// ---------------- V transpose: qkv_bf v-part [tok][d] -> vt[b][kvh][d][tok] ----------------
__global__ __launch_bounds__(256)
void vtrans_kernel(const u16* __restrict__ qkv, u16* __restrict__ vt) {
  __shared__ u16 tile[64][72];
  const int tid = threadIdx.x;
  const int t0 = blockIdx.x * 64, kvh = blockIdx.y, b = blockIdx.z;
  const int r = tid >> 2, c16 = (tid & 3) * 16;
  const u16* src = qkv + (size_t)(b * 2048 + t0 + r) * 1536 + 1280 + kvh * 64 + c16;
  *(uint4*)&tile[r][c16] = *(const uint4*)src;
  *(uint4*)&tile[r][c16 + 8] = *(const uint4*)(src + 8);
  __syncthreads();
  const int d = tid >> 2, t16 = (tid & 3) * 16;
  u16 o[16];
#pragma unroll
  for (int j = 0; j < 16; ++j) o[j] = tile[t16 + j][d];
  u16* dst = vt + (size_t)((b * 4 + kvh) * 64 + d) * 2048 + t0 + t16;
  *(uint4*)dst = *(uint4*)&o[0];
  *(uint4*)(dst + 8) = *(uint4*)&o[8];
}

// ---------------- MFMA flash attention ----------------
// grid (32 qtile, 16 h, 2 b), block 256 (4 waves). Each wave owns a 16-query strip.
// S^T = K·Q^T (rows=key, cols=q) so softmax'd P packs 4 consecutive keys -> b64 LDS writes,
// and P re-reads key-contiguous as the A-operand of PV. V comes pre-transposed from vtrans.
__global__ __launch_bounds__(256)
void attn_kernel(const u16* __restrict__ qkvbf, const u16* __restrict__ vt,
                 u16* __restrict__ ybf) {
  __shared__ u16 Ks[64 * 72];
  __shared__ u16 Vts[64 * 72];
  __shared__ u16 Ps[64 * 72];
  const int qt = blockIdx.x, h = blockIdx.y, b = blockIdx.z;
  const int kvh = h >> 2, q0 = qt * 64;
  const int tid = threadIdx.x, lane = tid & 63, w = tid >> 6;
  const int l15 = lane & 15, quad = lane >> 4;

  // Q fragments (B operand: n=q row = q0+w*16+l15, k=d), held in regs for all chunks
  const u16* qrow = qkvbf + (size_t)(b * 2048 + q0 + w * 16 + l15) * 1536 + h * 64 + quad * 8;
  const bf16x8 qf0 = *(const bf16x8*)qrow;
  const bf16x8 qf1 = *(const bf16x8*)(qrow + 32);

  // staging mapping: 64 rows x 64 bf16, 4 threads/row each 16 cols
  const int sr = tid >> 2, sc = (tid & 3) * 16;
  const u16* kbase = qkvbf + (size_t)(b * 2048 + sr) * 1536 + 1024 + kvh * 64 + sc;
  const u16* vbase = vt + (size_t)((b * 4 + kvh) * 64 + sr) * 2048 + sc;

  f32x4 O[4];
#pragma unroll
  for (int jd = 0; jd < 4; ++jd) O[jd] = f32x4{0.f, 0.f, 0.f, 0.f};
  float m_i = -1e30f, l_i = 0.f;
  const float slope = exp2f(-0.5f * (float)(h + 1));
  const int c_lo = (q0 >= 512) ? (q0 - 512) : 0;
  const int myq = q0 + w * 16 + l15;

  for (int c = c_lo; c <= q0; c += 64) {
    __syncthreads();
    {
      const u16* kp = kbase + (size_t)c * 1536;
      const u16* vp = vbase + c;
      uint4 ka = *(const uint4*)kp, kb = *(const uint4*)(kp + 8);
      uint4 va = *(const uint4*)vp, vb = *(const uint4*)(vp + 8);
      *(uint4*)&Ks[sr * 72 + sc] = ka;
      *(uint4*)&Ks[sr * 72 + sc + 8] = kb;
      *(uint4*)&Vts[sr * 72 + sc] = va;
      *(uint4*)&Vts[sr * 72 + sc + 8] = vb;
    }
    __syncthreads();

    // S^T strip: 4 key-tiles x (this wave's 16 q)
    f32x4 st[4];
#pragma unroll
    for (int i = 0; i < 4; ++i) {
      bf16x8 a0 = *(const bf16x8*)&Ks[(i * 16 + l15) * 72 + quad * 8];
      bf16x8 a1 = *(const bf16x8*)&Ks[(i * 16 + l15) * 72 + 32 + quad * 8];
      f32x4 z = f32x4{0.f, 0.f, 0.f, 0.f};
      z = __builtin_amdgcn_mfma_f32_16x16x32_bf16(a0, qf0, z, 0, 0, 0);
      st[i] = __builtin_amdgcn_mfma_f32_16x16x32_bf16(a1, qf1, z, 0, 0, 0);
    }

    // online softmax; lane owns column q=myq, 16 keys = i*16 + quad*4 + r
    float sv[4][4];
    float rm = -1e30f;
#pragma unroll
    for (int i = 0; i < 4; ++i) {
#pragma unroll
      for (int r = 0; r < 4; ++r) {
        const int key = c + i * 16 + quad * 4 + r;
        const int rel = key - myq;
        float val = (rel > 0 || rel < -512) ? -1e30f
                                            : st[i][r] * 0.125f + slope * (float)rel;
        sv[i][r] = val;
        rm = fmaxf(rm, val);
      }
    }
    rm = fmaxf(rm, __shfl_xor(rm, 16));
    rm = fmaxf(rm, __shfl_xor(rm, 32));
    const float mn = fmaxf(m_i, rm);
    const float alpha = __expf(m_i - mn);
    float ls = 0.f;
#pragma unroll
    for (int i = 0; i < 4; ++i) {
      float p0 = __expf(sv[i][0] - mn);
      float p1 = __expf(sv[i][1] - mn);
      float p2 = __expf(sv[i][2] - mn);
      float p3 = __expf(sv[i][3] - mn);
      ls += (p0 + p1) + (p2 + p3);
      uint2 pw;
      pw.x = (u32)f2bf(p0) | ((u32)f2bf(p1) << 16);
      pw.y = (u32)f2bf(p2) | ((u32)f2bf(p3) << 16);
      *(uint2*)&Ps[(w * 16 + l15) * 72 + i * 16 + quad * 4] = pw;
    }
    ls += __shfl_xor(ls, 16);
    ls += __shfl_xor(ls, 32);
    l_i = l_i * alpha + ls;
    m_i = mn;

    // rescale O rows (q = w*16 + quad*4 + r) by alpha of that q
    float ar[4];
#pragma unroll
    for (int r = 0; r < 4; ++r) ar[r] = __shfl(alpha, quad * 4 + r);
#pragma unroll
    for (int jd = 0; jd < 4; ++jd)
#pragma unroll
      for (int r = 0; r < 4; ++r) O[jd][r] *= ar[r];

    __syncthreads();  // make P visible (cross-lane) before fragment reads

    // PV: O[q][d] += P[q][key] * V^T[d][key]
    bf16x8 pf0 = *(const bf16x8*)&Ps[(w * 16 + l15) * 72 + quad * 8];
    bf16x8 pf1 = *(const bf16x8*)&Ps[(w * 16 + l15) * 72 + 32 + quad * 8];
#pragma unroll
    for (int jd = 0; jd < 4; ++jd) {
      bf16x8 v0 = *(const bf16x8*)&Vts[(jd * 16 + l15) * 72 + quad * 8];
      bf16x8 v1 = *(const bf16x8*)&Vts[(jd * 16 + l15) * 72 + 32 + quad * 8];
      O[jd] = __builtin_amdgcn_mfma_f32_16x16x32_bf16(pf0, v0, O[jd], 0, 0, 0);
      O[jd] = __builtin_amdgcn_mfma_f32_16x16x32_bf16(pf1, v1, O[jd], 0, 0, 0);
    }
  }

  // epilogue: divide by l (per q row) and store bf16
  float lr[4];
#pragma unroll
  for (int r = 0; r < 4; ++r) lr[r] = __shfl(l_i, quad * 4 + r);
#pragma unroll
  for (int r = 0; r < 4; ++r) {
    const float inv = 1.0f / lr[r];
    u16* orow = ybf + (size_t)(b * 2048 + q0 + w * 16 + quad * 4 + r) * 1024 + h * 64 + l15;
#pragma unroll
    for (int jd = 0; jd < 4; ++jd) orow[jd * 16] = f2bf(O[jd][r] * inv);
  }
}

// ---------------- launch ----------------
extern "C" void kernel_launch(void* const* d_in, const int* in_sizes, int n_in,
                              void* d_out, int out_size, void* d_ws, size_t ws_size,
                              hipStream_t stream) {
  const float* x = (const float*)d_in[0];
  const float* wq = (const float*)d_in[1];
  const float* wk = (const float*)d_in[2];
  const float* wv = (const float*)d_in[3];
  const float* wo = (const float*)d_in[4];
  const float* qnw = (const float*)d_in[5];
  const float* knw = (const float*)d_in[6];
  float* out = (float*)d_out;
  char* ws = (char*)d_ws;

  // workspace layout (bytes), total ~35 MB
  u16* x_bf = (u16*)(ws);                     // 4096x1024
  u16* wcat_bf = (u16*)(ws + 8388608);        // 1536x1024
  u16* wo_bf = (u16*)(ws + 11534336);         // 1024x1024
  u16* qkv_bf = (u16*)(ws + 13631488);        // 4096x1536
  u16* vt_bf = (u16*)(ws + 26214400);         // 2x4x64x2048
  u16* y_bf = (u16*)(ws + 28311552);          // 4096x1024

  cvt_kernel<<<4096, 256, 0, stream>>>(x, x_bf, 4194304);
  cvt_kernel<<<1024, 256, 0, stream>>>(wq, wcat_bf, 1048576);
  cvt_kernel<<<256, 256, 0, stream>>>(wk, wcat_bf + 1048576, 262144);
  cvt_kernel<<<256, 256, 0, stream>>>(wv, wcat_bf + 1310720, 262144);
  cvt_kernel<<<1024, 256, 0, stream>>>(wo, wo_bf, 1048576);

  gemm_bt_kernel<u16><<<dim3(12, 32), 256, 0, stream>>>(x_bf, wcat_bf, qkv_bf, 4096, 1536, 1024);
  rmsnorm_kernel<<<4096, 256, 0, stream>>>(qkv_bf, qnw, knw);
  vtrans_kernel<<<dim3(32, 4, 2), 256, 0, stream>>>(qkv_bf, vt_bf);
  attn_kernel<<<dim3(32, 16, 2), 256, 0, stream>>>(qkv_bf, vt_bf, y_bf);
  gemm_bt_kernel<float><<<dim3(8, 32), 256, 0, stream>>>(y_bf, wo_bf, out, 4096, 1024, 1024);
}

// Round 3
// 180.902 us; speedup vs baseline: 1.7188x; 1.0343x over previous
//
#include <hip/hip_runtime.h>

typedef unsigned short u16;
typedef unsigned int u32;

typedef __bf16 bf16x8 __attribute__((ext_vector_type(8)));
typedef float f32x4 __attribute__((ext_vector_type(4)));

__device__ __forceinline__ u16 f2bf(float f) {
  u32 u = __builtin_bit_cast(u32, f);
  u32 r = (u + 0x7fffu + ((u >> 16) & 1u)) >> 16;  // RNE
  return (u16)r;
}
__device__ __forceinline__ float bf2f(u16 v) {
  u32 u = (u32)v << 16;
  return __builtin_bit_cast(float, u);
}

// async global->LDS, 16B per lane; lds dest = wave-uniform base + lane*16B
typedef const __attribute__((address_space(1))) void* gas_ptr;
typedef __attribute__((address_space(3))) void* las_ptr;
__device__ __forceinline__ void gl2lds16(const void* g, void* l) {
  __builtin_amdgcn_global_load_lds((gas_ptr)g, (las_ptr)l, 16, 0, 0);
}

// ---------------- fused f32 -> bf16 convert for all 5 tensors ----------------
// unit = 4 elems/thread. ranges: x 1048576 | wq 262144 | wk 65536 | wv 65536 | wo 262144
__global__ __launch_bounds__(256)
void cvt_all_kernel(const float* __restrict__ x, const float* __restrict__ wq,
                    const float* __restrict__ wk, const float* __restrict__ wv,
                    const float* __restrict__ wo, u16* __restrict__ x_bf,
                    u16* __restrict__ wcat_bf, u16* __restrict__ wo_bf) {
  int t = blockIdx.x * 256 + threadIdx.x;
  const float* src;
  u16* dst;
  if (t < 1048576) {
    src = x; dst = x_bf;
  } else if (t < 1310720) {
    src = wq; dst = wcat_bf; t -= 1048576;
  } else if (t < 1376256) {
    src = wk; dst = wcat_bf + 1048576; t -= 1310720;
  } else if (t < 1441792) {
    src = wv; dst = wcat_bf + 1310720; t -= 1376256;
  } else {
    src = wo; dst = wo_bf; t -= 1441792;
  }
  const int i = t * 4;
  float4 v = *(const float4*)(src + i);
  uint2 p;
  p.x = (u32)f2bf(v.x) | ((u32)f2bf(v.y) << 16);
  p.y = (u32)f2bf(v.z) | ((u32)f2bf(v.w) << 16);
  *(uint2*)(dst + i) = p;
}

// ---------------- bf16 MFMA GEMM: C[M][N] = A[M][K] * B[N][K]^T ----------------
// 128x128 tile, BK=32, 4 waves 2x2, global_load_lds width-16 staging (m97 pattern).
template <typename OutT>
__global__ __launch_bounds__(256)
void gemm_bt_kernel(const u16* __restrict__ A, const u16* __restrict__ B,
                    OutT* __restrict__ C, int M, int N, int K) {
  __shared__ u16 As[128 * 32];
  __shared__ u16 Bs[128 * 32];
  const int tid = threadIdx.x;
  const int lane = tid & 63;
  const int wave = tid >> 6;
  const int wm = (wave >> 1) * 64;
  const int wn = (wave & 1) * 64;
  const int l15 = lane & 15;
  const int qk = (lane >> 4) * 8;
  const size_t bm = (size_t)blockIdx.y * 128;
  const size_t bn = (size_t)blockIdx.x * 128;

  f32x4 acc[4][4];
#pragma unroll
  for (int i = 0; i < 4; ++i)
#pragma unroll
    for (int j = 0; j < 4; ++j) acc[i][j] = f32x4{0.f, 0.f, 0.f, 0.f};

  const int r0 = tid >> 2;        // global row within tile half
  const int c0 = (tid & 3) * 8;   // k offset
  const u16* Ab = A + (bm + r0) * (size_t)K + c0;
  const u16* Bb = B + (bn + r0) * (size_t)K + c0;
  const int wbase = wave * 512;   // u16 offset of this wave's 1KB LDS strip

  for (int k0 = 0; k0 < K; k0 += 32) {
    __syncthreads();
    gl2lds16(Ab + k0, &As[wbase]);
    gl2lds16(Ab + (size_t)64 * K + k0, &As[2048 + wbase]);
    gl2lds16(Bb + k0, &Bs[wbase]);
    gl2lds16(Bb + (size_t)64 * K + k0, &Bs[2048 + wbase]);
    __syncthreads();
    bf16x8 af[4], bfr[4];
#pragma unroll
    for (int i = 0; i < 4; ++i)
      af[i] = *(const bf16x8*)(&As[(wm + i * 16 + l15) * 32 + qk]);
#pragma unroll
    for (int j = 0; j < 4; ++j)
      bfr[j] = *(const bf16x8*)(&Bs[(wn + j * 16 + l15) * 32 + qk]);
#pragma unroll
    for (int i = 0; i < 4; ++i)
#pragma unroll
      for (int j = 0; j < 4; ++j)
        acc[i][j] = __builtin_amdgcn_mfma_f32_16x16x32_bf16(af[i], bfr[j], acc[i][j], 0, 0, 0);
  }

  const int rq = (lane >> 4) * 4;
#pragma unroll
  for (int i = 0; i < 4; ++i) {
#pragma unroll
    for (int r = 0; r < 4; ++r) {
      OutT* crow = C + (bm + wm + i * 16 + rq + r) * (size_t)N + bn + wn + l15;
#pragma unroll
      for (int j = 0; j < 4; ++j) {
        if constexpr (sizeof(OutT) == 2)
          crow[j * 16] = f2bf(acc[i][j][r]);
        else
          crow[j * 16] = acc[i][j][r];
      }
    }
  }
}

// ---------------- in-place bf16 RMSNorm of q (1024) and k (256) per token ----------------
__global__ __launch_bounds__(256)
void rmsnorm_kernel(u16* __restrict__ qkv, const float* __restrict__ qw,
                    const float* __restrict__ kw) {
  __shared__ float red[4];
  const int tid = threadIdx.x;
  u16* row = qkv + (size_t)blockIdx.x * 1536;
  uint2 pk = *(const uint2*)(row + tid * 4);
  float v0 = bf2f((u16)pk.x), v1 = bf2f((u16)(pk.x >> 16));
  float v2 = bf2f((u16)pk.y), v3 = bf2f((u16)(pk.y >> 16));
  float ss = v0 * v0 + v1 * v1 + v2 * v2 + v3 * v3;
#pragma unroll
  for (int off = 32; off > 0; off >>= 1) ss += __shfl_down(ss, off);
  if ((tid & 63) == 0) red[tid >> 6] = ss;
  __syncthreads();
  float tot = red[0] + red[1] + red[2] + red[3];
  float rn = rsqrtf(tot * (1.0f / 1024.0f) + 1e-6f);
  float4 w = *(const float4*)(qw + tid * 4);
  uint2 po;
  po.x = (u32)f2bf(v0 * rn * w.x) | ((u32)f2bf(v1 * rn * w.y) << 16);
  po.y = (u32)f2bf(v2 * rn * w.z) | ((u32)f2bf(v3 * rn * w.w) << 16);
  *(uint2*)(row + tid * 4) = po;
  if (tid < 64) {
    uint2 kp = *(const uint2*)(row + 1024 + tid * 4);
    float k0 = bf2f((u16)kp.x), k1 = bf2f((u16)(kp.x >> 16));
    float k2 = bf2f((u16)kp.y), k3 = bf2f((u16)(kp.y >> 16));
    float sk = k0 * k0 + k1 * k1 + k2 * k2 + k3 * k3;
#pragma unroll
    for (int off = 32; off > 0; off >>= 1) sk += __shfl_down(sk, off);
    float tk = __shfl(sk, 0);
    float rk = rsqrtf(tk * (1.0f / 256.0f) + 1e-6f);
    float4 w2 = *(const float4*)(kw + tid * 4);
    uint2 ko;
    ko.x = (u32)f2bf(k0 * rk * w2.x) | ((u32)f2bf(k1 * rk * w2.y) << 16);
    ko.y = (u32)f2bf(k2 * rk * w2.z) | ((u32)f2bf(k3 * rk * w2.w) << 16);
    *(uint2*)(row + 1024 + tid * 4) = ko;
  }
}

// ---------------- V transpose: qkv_bf v-part [tok][d] -> vt[b][kvh][d][tok] ----------------
__global__ __launch_bounds__(256)
void vtrans_kernel(const u16* __restrict__ qkv, u16* __restrict__ vt) {
  __shared__ u16 tile[64][72];
  const int tid = threadIdx.x;
  const int t0 = blockIdx.x * 64, kvh = blockIdx.y, b = blockIdx.z;
  const int r = tid >> 2, c16 = (tid & 3) * 16;
  const u16* src = qkv + (size_t)(b * 2048 + t0 + r) * 1536 + 1280 + kvh * 64 + c16;
  *(uint4*)&tile[r][c16] = *(const uint4*)src;
  *(uint4*)&tile[r][c16 + 8] = *(const uint4*)(src + 8);
  __syncthreads();
  const int d = tid >> 2, t16 = (tid & 3) * 16;
  u16 o[16];
#pragma unroll
  for (int j = 0; j < 16; ++j) o[j] = tile[t16 + j][d];
  u16* dst = vt + (size_t)((b * 4 + kvh) * 64 + d) * 2048 + t0 + t16;
  *(uint4*)dst = *(uint4*)&o[0];
  *(uint4*)(dst + 8) = *(uint4*)&o[8];
}

// ---------------- MFMA flash attention ----------------
__global__ __launch_bounds__(256)
void attn_kernel(const u16* __restrict__ qkvbf, const u16* __restrict__ vt,
                 u16* __restrict__ ybf) {
  __shared__ u16 Ks[64 * 72];
  __shared__ u16 Vts[64 * 72];
  __shared__ u16 Ps[64 * 72];
  const int qt = blockIdx.x, h = blockIdx.y, b = blockIdx.z;
  const int kvh = h >> 2, q0 = qt * 64;
  const int tid = threadIdx.x, lane = tid & 63, w = tid >> 6;
  const int l15 = lane & 15, quad = lane >> 4;

  const u16* qrow = qkvbf + (size_t)(b * 2048 + q0 + w * 16 + l15) * 1536 + h * 64 + quad * 8;
  const bf16x8 qf0 = *(const bf16x8*)qrow;
  const bf16x8 qf1 = *(const bf16x8*)(qrow + 32);

  const int sr = tid >> 2, sc = (tid & 3) * 16;
  const u16* kbase = qkvbf + (size_t)(b * 2048 + sr) * 1536 + 1024 + kvh * 64 + sc;
  const u16* vbase = vt + (size_t)((b * 4 + kvh) * 64 + sr) * 2048 + sc;

  f32x4 O[4];
#pragma unroll
  for (int jd = 0; jd < 4; ++jd) O[jd] = f32x4{0.f, 0.f, 0.f, 0.f};
  float m_i = -1e30f, l_i = 0.f;
  const float slope = exp2f(-0.5f * (float)(h + 1));
  const int c_lo = (q0 >= 512) ? (q0 - 512) : 0;
  const int myq = q0 + w * 16 + l15;

  for (int c = c_lo; c <= q0; c += 64) {
    __syncthreads();
    {
      const u16* kp = kbase + (size_t)c * 1536;
      const u16* vp = vbase + c;
      uint4 ka = *(const uint4*)kp, kb = *(const uint4*)(kp + 8);
      uint4 va = *(const uint4*)vp, vb = *(const uint4*)(vp + 8);
      *(uint4*)&Ks[sr * 72 + sc] = ka;
      *(uint4*)&Ks[sr * 72 + sc + 8] = kb;
      *(uint4*)&Vts[sr * 72 + sc] = va;
      *(uint4*)&Vts[sr * 72 + sc + 8] = vb;
    }
    __syncthreads();

    f32x4 st[4];
#pragma unroll
    for (int i = 0; i < 4; ++i) {
      bf16x8 a0 = *(const bf16x8*)&Ks[(i * 16 + l15) * 72 + quad * 8];
      bf16x8 a1 = *(const bf16x8*)&Ks[(i * 16 + l15) * 72 + 32 + quad * 8];
      f32x4 z = f32x4{0.f, 0.f, 0.f, 0.f};
      z = __builtin_amdgcn_mfma_f32_16x16x32_bf16(a0, qf0, z, 0, 0, 0);
      st[i] = __builtin_amdgcn_mfma_f32_16x16x32_bf16(a1, qf1, z, 0, 0, 0);
    }

    float sv[4][4];
    float rm = -1e30f;
#pragma unroll
    for (int i = 0; i < 4; ++i) {
#pragma unroll
      for (int r = 0; r < 4; ++r) {
        const int key = c + i * 16 + quad * 4 + r;
        const int rel = key - myq;
        float val = (rel > 0 || rel < -512) ? -1e30f
                                            : st[i][r] * 0.125f + slope * (float)rel;
        sv[i][r] = val;
        rm = fmaxf(rm, val);
      }
    }
    rm = fmaxf(rm, __shfl_xor(rm, 16));
    rm = fmaxf(rm, __shfl_xor(rm, 32));
    const float mn = fmaxf(m_i, rm);
    const float alpha = __expf(m_i - mn);
    float ls = 0.f;
#pragma unroll
    for (int i = 0; i < 4; ++i) {
      float p0 = __expf(sv[i][0] - mn);
      float p1 = __expf(sv[i][1] - mn);
      float p2 = __expf(sv[i][2] - mn);
      float p3 = __expf(sv[i][3] - mn);
      ls += (p0 + p1) + (p2 + p3);
      uint2 pw;
      pw.x = (u32)f2bf(p0) | ((u32)f2bf(p1) << 16);
      pw.y = (u32)f2bf(p2) | ((u32)f2bf(p3) << 16);
      *(uint2*)&Ps[(w * 16 + l15) * 72 + i * 16 + quad * 4] = pw;
    }
    ls += __shfl_xor(ls, 16);
    ls += __shfl_xor(ls, 32);
    l_i = l_i * alpha + ls;
    m_i = mn;

    float ar[4];
#pragma unroll
    for (int r = 0; r < 4; ++r) ar[r] = __shfl(alpha, quad * 4 + r);
#pragma unroll
    for (int jd = 0; jd < 4; ++jd)
#pragma unroll
      for (int r = 0; r < 4; ++r) O[jd][r] *= ar[r];

    __syncthreads();

    bf16x8 pf0 = *(const bf16x8*)&Ps[(w * 16 + l15) * 72 + quad * 8];
    bf16x8 pf1 = *(const bf16x8*)&Ps[(w * 16 + l15) * 72 + 32 + quad * 8];
#pragma unroll
    for (int jd = 0; jd < 4; ++jd) {
      bf16x8 v0 = *(const bf16x8*)&Vts[(jd * 16 + l15) * 72 + quad * 8];
      bf16x8 v1 = *(const bf16x8*)&Vts[(jd * 16 + l15) * 72 + 32 + quad * 8];
      O[jd] = __builtin_amdgcn_mfma_f32_16x16x32_bf16(pf0, v0, O[jd], 0, 0, 0);
      O[jd] = __builtin_amdgcn_mfma_f32_16x16x32_bf16(pf1, v1, O[jd], 0, 0, 0);
    }
  }

  float lr[4];
#pragma unroll
  for (int r = 0; r < 4; ++r) lr[r] = __shfl(l_i, quad * 4 + r);
#pragma unroll
  for (int r = 0; r < 4; ++r) {
    const float inv = 1.0f / lr[r];
    u16* orow = ybf + (size_t)(b * 2048 + q0 + w * 16 + quad * 4 + r) * 1024 + h * 64 + l15;
#pragma unroll
    for (int jd = 0; jd < 4; ++jd) orow[jd * 16] = f2bf(O[jd][r] * inv);
  }
}

// ---------------- launch ----------------
extern "C" void kernel_launch(void* const* d_in, const int* in_sizes, int n_in,
                              void* d_out, int out_size, void* d_ws, size_t ws_size,
                              hipStream_t stream) {
  const float* x = (const float*)d_in[0];
  const float* wq = (const float*)d_in[1];
  const float* wk = (const float*)d_in[2];
  const float* wv = (const float*)d_in[3];
  const float* wo = (const float*)d_in[4];
  const float* qnw = (const float*)d_in[5];
  const float* knw = (const float*)d_in[6];
  float* out = (float*)d_out;
  char* ws = (char*)d_ws;

  u16* x_bf = (u16*)(ws);                     // 4096x1024
  u16* wcat_bf = (u16*)(ws + 8388608);        // 1536x1024
  u16* wo_bf = (u16*)(ws + 11534336);         // 1024x1024
  u16* qkv_bf = (u16*)(ws + 13631488);        // 4096x1536
  u16* vt_bf = (u16*)(ws + 26214400);         // 2x4x64x2048
  u16* y_bf = (u16*)(ws + 28311552);          // 4096x1024

  cvt_all_kernel<<<6656, 256, 0, stream>>>(x, wq, wk, wv, wo, x_bf, wcat_bf, wo_bf);

  gemm_bt_kernel<u16><<<dim3(12, 32), 256, 0, stream>>>(x_bf, wcat_bf, qkv_bf, 4096, 1536, 1024);
  rmsnorm_kernel<<<4096, 256, 0, stream>>>(qkv_bf, qnw, knw);
  vtrans_kernel<<<dim3(32, 4, 2), 256, 0, stream>>>(qkv_bf, vt_bf);
  attn_kernel<<<dim3(32, 16, 2), 256, 0, stream>>>(qkv_bf, vt_bf, y_bf);
  gemm_bt_kernel<float><<<dim3(8, 32), 256, 0, stream>>>(y_bf, wo_bf, out, 4096, 1024, 1024);
}

// Round 4
// 171.856 us; speedup vs baseline: 1.8093x; 1.0526x over previous
//
#include <hip/hip_runtime.h>

typedef unsigned short u16;
typedef unsigned int u32;

typedef __bf16 bf16x8 __attribute__((ext_vector_type(8)));
typedef float f32x4 __attribute__((ext_vector_type(4)));

__device__ __forceinline__ u16 f2bf(float f) {
  u32 u = __builtin_bit_cast(u32, f);
  u32 r = (u + 0x7fffu + ((u >> 16) & 1u)) >> 16;  // RNE
  return (u16)r;
}
__device__ __forceinline__ float bf2f(u16 v) {
  u32 u = (u32)v << 16;
  return __builtin_bit_cast(float, u);
}

// ---------------- fused f32 -> bf16 convert for all 5 tensors ----------------
__global__ __launch_bounds__(256)
void cvt_all_kernel(const float* __restrict__ x, const float* __restrict__ wq,
                    const float* __restrict__ wk, const float* __restrict__ wv,
                    const float* __restrict__ wo, u16* __restrict__ x_bf,
                    u16* __restrict__ wcat_bf, u16* __restrict__ wo_bf) {
  int t = blockIdx.x * 256 + threadIdx.x;
  const float* src;
  u16* dst;
  if (t < 1048576) {
    src = x; dst = x_bf;
  } else if (t < 1310720) {
    src = wq; dst = wcat_bf; t -= 1048576;
  } else if (t < 1376256) {
    src = wk; dst = wcat_bf + 1048576; t -= 1310720;
  } else if (t < 1441792) {
    src = wv; dst = wcat_bf + 1310720; t -= 1376256;
  } else {
    src = wo; dst = wo_bf; t -= 1441792;
  }
  const int i = t * 4;
  float4 v = *(const float4*)(src + i);
  uint2 p;
  p.x = (u32)f2bf(v.x) | ((u32)f2bf(v.y) << 16);
  p.y = (u32)f2bf(v.z) | ((u32)f2bf(v.w) << 16);
  *(uint2*)(dst + i) = p;
}

// ---------------- bf16 MFMA GEMM: C[M][N] = A[M][K] * B[N][K]^T ----------------
// 64x128 tile (more blocks -> 2-3/CU), BK=32, 4 waves 2x2 (wave tile 32x64),
// register-staged software pipeline: prefetch tile k+1 into regs before MFMA.
template <typename OutT>
__global__ __launch_bounds__(256)
void gemm_bt_kernel(const u16* __restrict__ A, const u16* __restrict__ B,
                    OutT* __restrict__ C, int M, int N, int K) {
  __shared__ u16 As[64 * 32];    // 4 KB
  __shared__ u16 Bs[128 * 32];   // 8 KB
  const int tid = threadIdx.x;
  const int lane = tid & 63;
  const int wave = tid >> 6;
  const int wm = (wave >> 1) * 32;   // 0 / 32
  const int wn = (wave & 1) * 64;    // 0 / 64
  const int l15 = lane & 15;
  const int qk = (lane >> 4) * 8;
  const size_t bm = (size_t)blockIdx.y * 64;
  const size_t bn = (size_t)blockIdx.x * 128;

  f32x4 acc[2][4];
#pragma unroll
  for (int i = 0; i < 2; ++i)
#pragma unroll
    for (int j = 0; j < 4; ++j) acc[i][j] = f32x4{0.f, 0.f, 0.f, 0.f};

  const int r0 = tid >> 2;        // 0..63
  const int c0 = (tid & 3) * 8;   // k offset
  const u16* Ab = A + (bm + r0) * (size_t)K + c0;
  const u16* Bb = B + (bn + r0) * (size_t)K + c0;

  uint4 ar = *(const uint4*)(Ab);
  uint4 br0 = *(const uint4*)(Bb);
  uint4 br1 = *(const uint4*)(Bb + (size_t)64 * K);

  for (int k0 = 0; k0 < K; k0 += 32) {
    __syncthreads();
    *(uint4*)(&As[tid * 8]) = ar;
    *(uint4*)(&Bs[tid * 8]) = br0;
    *(uint4*)(&Bs[tid * 8 + 2048]) = br1;
    __syncthreads();
    const int kn = (k0 + 32 < K) ? k0 + 32 : 0;  // in-bounds dummy on last iter
    ar = *(const uint4*)(Ab + kn);
    br0 = *(const uint4*)(Bb + kn);
    br1 = *(const uint4*)(Bb + (size_t)64 * K + kn);
    bf16x8 af[2], bfr[4];
#pragma unroll
    for (int i = 0; i < 2; ++i)
      af[i] = *(const bf16x8*)(&As[(wm + i * 16 + l15) * 32 + qk]);
#pragma unroll
    for (int j = 0; j < 4; ++j)
      bfr[j] = *(const bf16x8*)(&Bs[(wn + j * 16 + l15) * 32 + qk]);
#pragma unroll
    for (int i = 0; i < 2; ++i)
#pragma unroll
      for (int j = 0; j < 4; ++j)
        acc[i][j] = __builtin_amdgcn_mfma_f32_16x16x32_bf16(af[i], bfr[j], acc[i][j], 0, 0, 0);
  }

  const int rq = (lane >> 4) * 4;
#pragma unroll
  for (int i = 0; i < 2; ++i) {
#pragma unroll
    for (int r = 0; r < 4; ++r) {
      OutT* crow = C + (bm + wm + i * 16 + rq + r) * (size_t)N + bn + wn + l15;
#pragma unroll
      for (int j = 0; j < 4; ++j) {
        if constexpr (sizeof(OutT) == 2)
          crow[j * 16] = f2bf(acc[i][j][r]);
        else
          crow[j * 16] = acc[i][j][r];
      }
    }
  }
}

// ---------------- fused: rmsnorm (blocks 0..4095) + V transpose (blocks 4096..4351) ----------------
__global__ __launch_bounds__(256)
void norm_vtrans_kernel(u16* __restrict__ qkv, const float* __restrict__ qw,
                        const float* __restrict__ kw, u16* __restrict__ vt) {
  __shared__ u16 shmem[64 * 72];
  const int bid = blockIdx.x;
  const int tid = threadIdx.x;
  if (bid < 4096) {
    // ---- RMSNorm of q (1024) and k (256) for token bid ----
    float* red = (float*)shmem;
    u16* row = qkv + (size_t)bid * 1536;
    uint2 pk = *(const uint2*)(row + tid * 4);
    float v0 = bf2f((u16)pk.x), v1 = bf2f((u16)(pk.x >> 16));
    float v2 = bf2f((u16)pk.y), v3 = bf2f((u16)(pk.y >> 16));
    float ss = v0 * v0 + v1 * v1 + v2 * v2 + v3 * v3;
#pragma unroll
    for (int off = 32; off > 0; off >>= 1) ss += __shfl_down(ss, off);
    if ((tid & 63) == 0) red[tid >> 6] = ss;
    __syncthreads();
    float tot = red[0] + red[1] + red[2] + red[3];
    float rn = rsqrtf(tot * (1.0f / 1024.0f) + 1e-6f);
    float4 w = *(const float4*)(qw + tid * 4);
    uint2 po;
    po.x = (u32)f2bf(v0 * rn * w.x) | ((u32)f2bf(v1 * rn * w.y) << 16);
    po.y = (u32)f2bf(v2 * rn * w.z) | ((u32)f2bf(v3 * rn * w.w) << 16);
    *(uint2*)(row + tid * 4) = po;
    if (tid < 64) {
      uint2 kp = *(const uint2*)(row + 1024 + tid * 4);
      float k0 = bf2f((u16)kp.x), k1 = bf2f((u16)(kp.x >> 16));
      float k2 = bf2f((u16)kp.y), k3 = bf2f((u16)(kp.y >> 16));
      float sk = k0 * k0 + k1 * k1 + k2 * k2 + k3 * k3;
#pragma unroll
      for (int off = 32; off > 0; off >>= 1) sk += __shfl_down(sk, off);
      float tk = __shfl(sk, 0);
      float rk = rsqrtf(tk * (1.0f / 256.0f) + 1e-6f);
      float4 w2 = *(const float4*)(kw + tid * 4);
      uint2 ko;
      ko.x = (u32)f2bf(k0 * rk * w2.x) | ((u32)f2bf(k1 * rk * w2.y) << 16);
      ko.y = (u32)f2bf(k2 * rk * w2.z) | ((u32)f2bf(k3 * rk * w2.w) << 16);
      *(uint2*)(row + 1024 + tid * 4) = ko;
    }
  } else {
    // ---- V transpose: qkv v-part [tok][d] -> vt[b][kvh][d][tok] ----
    const int e = bid - 4096;
    const int t0 = (e & 31) * 64, kvh = (e >> 5) & 3, b = e >> 7;
    u16(*tile)[72] = (u16(*)[72])shmem;
    const int r = tid >> 2, c16 = (tid & 3) * 16;
    const u16* src = qkv + (size_t)(b * 2048 + t0 + r) * 1536 + 1280 + kvh * 64 + c16;
    *(uint4*)&tile[r][c16] = *(const uint4*)src;
    *(uint4*)&tile[r][c16 + 8] = *(const uint4*)(src + 8);
    __syncthreads();
    const int d = tid >> 2, t16 = (tid & 3) * 16;
    u16 o[16];
#pragma unroll
    for (int j = 0; j < 16; ++j) o[j] = tile[t16 + j][d];
    u16* dst = vt + (size_t)((b * 4 + kvh) * 64 + d) * 2048 + t0 + t16;
    *(uint4*)dst = *(uint4*)&o[0];
    *(uint4*)(dst + 8) = *(uint4*)&o[8];
  }
}

// ---------------- MFMA flash attention ----------------
// grid (32 qtile, 16 h, 2 b), 4 waves; wave owns a 16-q strip. S^T = K.Q^T.
// K/V register prefetch pipeline; 2 barriers/chunk (P is wave-private);
// exp2-domain softmax; maskless fast path for interior chunks.
__global__ __launch_bounds__(256)
void attn_kernel(const u16* __restrict__ qkvbf, const u16* __restrict__ vt,
                 u16* __restrict__ ybf) {
  __shared__ u16 Ks[64 * 72];
  __shared__ u16 Vts[64 * 72];
  __shared__ u16 Ps[64 * 72];
  const int qt = blockIdx.x, h = blockIdx.y, b = blockIdx.z;
  const int kvh = h >> 2, q0 = qt * 64;
  const int tid = threadIdx.x, lane = tid & 63, w = tid >> 6;
  const int l15 = lane & 15, quad = lane >> 4;

  const u16* qrow = qkvbf + (size_t)(b * 2048 + q0 + w * 16 + l15) * 1536 + h * 64 + quad * 8;
  const bf16x8 qf0 = *(const bf16x8*)qrow;
  const bf16x8 qf1 = *(const bf16x8*)(qrow + 32);

  const int sr = tid >> 2, sc = (tid & 3) * 16;
  const u16* kbase = qkvbf + (size_t)(b * 2048 + sr) * 1536 + 1024 + kvh * 64 + sc;
  const u16* vbase = vt + (size_t)((b * 4 + kvh) * 64 + sr) * 2048 + sc;

  f32x4 O[4];
#pragma unroll
  for (int jd = 0; jd < 4; ++jd) O[jd] = f32x4{0.f, 0.f, 0.f, 0.f};
  float m_i = -1e30f, l_i = 0.f;
  const float LOG2E = 1.44269504f;
  const float sc2 = 0.125f * LOG2E;                       // score scale, log2 domain
  const float slope2 = exp2f(-0.5f * (float)(h + 1)) * LOG2E;  // alibi slope, log2 domain
  const int c_lo = (q0 >= 512) ? (q0 - 512) : 0;
  const int myq = q0 + w * 16 + l15;
  const int myq_lo = q0 + w * 16;

  // prefetch first chunk
  uint4 kr0, kr1, vr0, vr1;
  {
    const u16* kp = kbase + (size_t)c_lo * 1536;
    const u16* vp = vbase + c_lo;
    kr0 = *(const uint4*)kp;  kr1 = *(const uint4*)(kp + 8);
    vr0 = *(const uint4*)vp;  vr1 = *(const uint4*)(vp + 8);
  }

  for (int c = c_lo; c <= q0; c += 64) {
    __syncthreads();  // prior chunk's Ks/Vts fragment reads done
    *(uint4*)&Ks[sr * 72 + sc] = kr0;
    *(uint4*)&Ks[sr * 72 + sc + 8] = kr1;
    *(uint4*)&Vts[sr * 72 + sc] = vr0;
    *(uint4*)&Vts[sr * 72 + sc + 8] = vr1;
    __syncthreads();
    // prefetch next chunk into regs (dummy reload of c_lo on last iter)
    {
      const int cn = (c + 64 <= q0) ? c + 64 : c_lo;
      const u16* kp = kbase + (size_t)cn * 1536;
      const u16* vp = vbase + cn;
      kr0 = *(const uint4*)kp;  kr1 = *(const uint4*)(kp + 8);
      vr0 = *(const uint4*)vp;  vr1 = *(const uint4*)(vp + 8);
    }

    // S^T strip: 4 key-tiles x (this wave's 16 q)
    f32x4 st[4];
#pragma unroll
    for (int i = 0; i < 4; ++i) {
      bf16x8 a0 = *(const bf16x8*)&Ks[(i * 16 + l15) * 72 + quad * 8];
      bf16x8 a1 = *(const bf16x8*)&Ks[(i * 16 + l15) * 72 + 32 + quad * 8];
      f32x4 z = f32x4{0.f, 0.f, 0.f, 0.f};
      z = __builtin_amdgcn_mfma_f32_16x16x32_bf16(a0, qf0, z, 0, 0, 0);
      st[i] = __builtin_amdgcn_mfma_f32_16x16x32_bf16(a1, qf1, z, 0, 0, 0);
    }

    // online softmax in log2 domain; lane owns col q=myq, keys i*16+quad*4+r
    float sv[4][4];
    float rm = -1e30f;
    const bool interior = (c + 63 <= myq_lo) && (c + 512 >= myq_lo + 15);
    if (interior) {
#pragma unroll
      for (int i = 0; i < 4; ++i)
#pragma unroll
        for (int r = 0; r < 4; ++r) {
          const int key = c + i * 16 + quad * 4 + r;
          float val = st[i][r] * sc2 + slope2 * (float)(key - myq);
          sv[i][r] = val;
          rm = fmaxf(rm, val);
        }
    } else {
#pragma unroll
      for (int i = 0; i < 4; ++i)
#pragma unroll
        for (int r = 0; r < 4; ++r) {
          const int key = c + i * 16 + quad * 4 + r;
          const int rel = key - myq;
          float val = (rel > 0 || rel < -512) ? -1e30f
                                              : st[i][r] * sc2 + slope2 * (float)rel;
          sv[i][r] = val;
          rm = fmaxf(rm, val);
        }
    }
    rm = fmaxf(rm, __shfl_xor(rm, 16));
    rm = fmaxf(rm, __shfl_xor(rm, 32));
    const float mn = fmaxf(m_i, rm);
    const float alpha = exp2f(m_i - mn);
    float ls = 0.f;
#pragma unroll
    for (int i = 0; i < 4; ++i) {
      float p0 = exp2f(sv[i][0] - mn);
      float p1 = exp2f(sv[i][1] - mn);
      float p2 = exp2f(sv[i][2] - mn);
      float p3 = exp2f(sv[i][3] - mn);
      ls += (p0 + p1) + (p2 + p3);
      uint2 pw;
      pw.x = (u32)f2bf(p0) | ((u32)f2bf(p1) << 16);
      pw.y = (u32)f2bf(p2) | ((u32)f2bf(p3) << 16);
      *(uint2*)&Ps[(w * 16 + l15) * 72 + i * 16 + quad * 4] = pw;
    }
    ls += __shfl_xor(ls, 16);
    ls += __shfl_xor(ls, 32);
    l_i = l_i * alpha + ls;
    m_i = mn;

    float ar[4];
#pragma unroll
    for (int r = 0; r < 4; ++r) ar[r] = __shfl(alpha, quad * 4 + r);
#pragma unroll
    for (int jd = 0; jd < 4; ++jd)
#pragma unroll
      for (int r = 0; r < 4; ++r) O[jd][r] *= ar[r];

    // P rows are wave-private (rows w*16..w*16+15): no barrier needed before re-read.
    bf16x8 pf0 = *(const bf16x8*)&Ps[(w * 16 + l15) * 72 + quad * 8];
    bf16x8 pf1 = *(const bf16x8*)&Ps[(w * 16 + l15) * 72 + 32 + quad * 8];
#pragma unroll
    for (int jd = 0; jd < 4; ++jd) {
      bf16x8 v0 = *(const bf16x8*)&Vts[(jd * 16 + l15) * 72 + quad * 8];
      bf16x8 v1 = *(const bf16x8*)&Vts[(jd * 16 + l15) * 72 + 32 + quad * 8];
      O[jd] = __builtin_amdgcn_mfma_f32_16x16x32_bf16(pf0, v0, O[jd], 0, 0, 0);
      O[jd] = __builtin_amdgcn_mfma_f32_16x16x32_bf16(pf1, v1, O[jd], 0, 0, 0);
    }
  }

  float lr[4];
#pragma unroll
  for (int r = 0; r < 4; ++r) lr[r] = __shfl(l_i, quad * 4 + r);
#pragma unroll
  for (int r = 0; r < 4; ++r) {
    const float inv = 1.0f / lr[r];
    u16* orow = ybf + (size_t)(b * 2048 + q0 + w * 16 + quad * 4 + r) * 1024 + h * 64 + l15;
#pragma unroll
    for (int jd = 0; jd < 4; ++jd) orow[jd * 16] = f2bf(O[jd][r] * inv);
  }
}

// ---------------- launch ----------------
extern "C" void kernel_launch(void* const* d_in, const int* in_sizes, int n_in,
                              void* d_out, int out_size, void* d_ws, size_t ws_size,
                              hipStream_t stream) {
  const float* x = (const float*)d_in[0];
  const float* wq = (const float*)d_in[1];
  const float* wk = (const float*)d_in[2];
  const float* wv = (const float*)d_in[3];
  const float* wo = (const float*)d_in[4];
  const float* qnw = (const float*)d_in[5];
  const float* knw = (const float*)d_in[6];
  float* out = (float*)d_out;
  char* ws = (char*)d_ws;

  u16* x_bf = (u16*)(ws);                     // 4096x1024
  u16* wcat_bf = (u16*)(ws + 8388608);        // 1536x1024
  u16* wo_bf = (u16*)(ws + 11534336);         // 1024x1024
  u16* qkv_bf = (u16*)(ws + 13631488);        // 4096x1536
  u16* vt_bf = (u16*)(ws + 26214400);         // 2x4x64x2048
  u16* y_bf = (u16*)(ws + 28311552);          // 4096x1024

  cvt_all_kernel<<<6656, 256, 0, stream>>>(x, wq, wk, wv, wo, x_bf, wcat_bf, wo_bf);

  gemm_bt_kernel<u16><<<dim3(12, 64), 256, 0, stream>>>(x_bf, wcat_bf, qkv_bf, 4096, 1536, 1024);
  norm_vtrans_kernel<<<4352, 256, 0, stream>>>(qkv_bf, qnw, knw, vt_bf);
  attn_kernel<<<dim3(32, 16, 2), 256, 0, stream>>>(qkv_bf, vt_bf, y_bf);
  gemm_bt_kernel<float><<<dim3(8, 64), 256, 0, stream>>>(y_bf, wo_bf, out, 4096, 1024, 1024);
}